// Round 1
// baseline (179.760 us; speedup 1.0000x reference)
//
#include <hip/hip_runtime.h>
#include <hip/hip_bf16.h>

#define B_ 8
#define H_ 8
#define S_ 1024
#define D_ 64
#define QT 64   // q rows per block (16 per wave)
#define KT 32   // k cols per tile

typedef float f32x4 __attribute__((ext_vector_type(4)));
typedef short s16x8 __attribute__((ext_vector_type(8)));

// (1/sqrt(2*D)) * log2(e): softmax done base-2
#define CSCALE ((float)(1.4426950408889634 / 11.313708498984761))

static __device__ __forceinline__ unsigned short f2bf(float f) {
    union { float f; unsigned u; } v; v.f = f;
    unsigned r = v.u + 0x7FFF + ((v.u >> 16) & 1);   // RNE
    return (unsigned short)(r >> 16);
}

// ---------------- pairs kernel: replicate reference IoU-argmax bit-exactly ----------------
__global__ __launch_bounds__(256) void pairs_kernel(const float* __restrict__ centers,
                                                    int* __restrict__ p0,
                                                    int* __restrict__ p1) {
#pragma clang fp contract(off)
    __shared__ float x0s[S_], y0s[S_], x1s[S_], y1s[S_], areas[S_], l1s[S_];
    const int b = blockIdx.y;
    const int t = threadIdx.x;
    for (int idx = t; idx < S_; idx += 256) {
        const float4 c = *reinterpret_cast<const float4*>(centers + ((size_t)b * S_ + idx) * 4);
        const float cx = c.x, cy = c.y, hh = c.z, ww = c.w;  // order: cx, cy, h, w
        const float x0 = cx - 0.5f * ww;
        const float y0 = cy - 0.5f * hh;
        const float x1 = cx + 0.5f * ww;
        const float y1 = cy + 0.5f * hh;
        x0s[idx] = x0; y0s[idx] = y0; x1s[idx] = x1; y1s[idx] = y1;
        areas[idx] = (x1 - x0) * (y1 - y0);
        l1s[idx] = fabsf(x1 - x0) + fabsf(y1 - y0);
    }
    __syncthreads();
    const int i = blockIdx.x * 128 + (t >> 1);
    const int half = t & 1;
    const float x0i = x0s[i], y0i = y0s[i], x1i = x1s[i], y1i = y1s[i], ai = areas[i];
    float best = -1e38f; int arg = 0;
    const int j0 = half * 512;
    for (int j = j0; j < j0 + 512; ++j) {
        // NOTE: replicates reference exactly, including maximum() used for BOTH mins and maxs
        float wx = fmaxf(x1i, x1s[j]) - fmaxf(x0i, x0s[j]);
        float wy = fmaxf(y1i, y1s[j]) - fmaxf(y0i, y0s[j]);
        wx = fmaxf(wx, 0.0f);
        wy = fmaxf(wy, 0.0f);
        const float inter = wx * wy;
        const float uni = (ai + areas[j]) - inter;
        float v = inter / uni;
        if (j == i) v = v - 1.0f;   // -eye AFTER the division, as in reference
        if (v > best) { best = v; arg = j; }   // first-occurrence-of-max semantics
    }
    // combine halves: lower-j half wins ties (argA < argB always)
    const float obest = __shfl_xor(best, 1);
    const int oarg = __shfl_xor(arg, 1);
    if (half == 0) {
        if (!(best >= obest)) { best = obest; arg = oarg; }
        const int partner = arg;
        const float l1i = l1s[i], l1p = l1s[partner];
        const int keep = (l1i >= l1p) ? 1 : 0;
        p0[b * S_ + i] = keep ? i : partner;
        p1[b * S_ + i] = keep ? partner : i;
    }
}

// ---------------- fused flash attention with gathered Q'/K' (head-dim 128), bf16 MFMA ----------------
__global__ __launch_bounds__(256) void attn_kernel(const float* __restrict__ q,
                                                   const float* __restrict__ k,
                                                   const float* __restrict__ v,
                                                   const int* __restrict__ p0,
                                                   const int* __restrict__ p1,
                                                   float* __restrict__ out) {
    __shared__ __align__(16) unsigned short Qs[QT][136];     // gathered Q' tile, bf16, padded
    __shared__ __align__(16) unsigned short Ks[KT][136];     // gathered K' tile
    __shared__ __align__(16) unsigned short Vs[D_][40];      // V^T tile: [d][kk]
    __shared__ __align__(16) unsigned short Ps[4][16][40];   // per-wave P tile [q][kk]

    const int tid = threadIdx.x;
    const int w = tid >> 6;          // wave 0..3
    const int lane = tid & 63;
    const int qtile = blockIdx.x;    // 0..15
    const int bh = blockIdx.y;       // 0..63
    const int b = bh >> 3;
    const int h = bh & 7;

    const size_t bh_off = (size_t)bh * S_ * D_;
    const float* qp = q + bh_off;
    const float* kp = k + bh_off;
    const float* vp = v + bh_off;
    const int* p0b = p0 + b * S_;
    const int* p1b = p1 + b * S_;

    // ---- stage this wave's 16 Q' rows (gathered, f32 -> bf16) ----
    {
        const int r0 = w * 16;
        for (int i = 0; i < 16; ++i) {
            const int grow = qtile * QT + r0 + i;
            const int i0 = p0b[grow], i1 = p1b[grow];
            const float a0 = qp[(size_t)i0 * D_ + lane];
            const float a1 = qp[(size_t)i1 * D_ + lane];
            Qs[r0 + i][lane] = f2bf(a0);
            Qs[r0 + i][64 + lane] = f2bf(a1);
        }
    }
    const int fr = lane & 15;   // fragment 16-index
    const int fg = lane >> 4;   // quadrant 0..3

    // load Q fragments: A-frag lane layout row=fr, k = 32*c + 8*fg + j
    s16x8 qf[4];
    {
        const unsigned short* qrow = &Qs[w * 16 + fr][0];
        for (int c = 0; c < 4; ++c)
            qf[c] = *reinterpret_cast<const s16x8*>(qrow + c * 32 + fg * 8);
    }

    f32x4 oacc[4] = {};           // O accumulator: 4 d-subtiles x 4 rows
    float m_run[4], l_run[4];
    for (int r = 0; r < 4; ++r) { m_run[r] = -1e30f; l_run[r] = 0.0f; }

    for (int kt = 0; kt < S_ / KT; ++kt) {
        __syncthreads();   // previous tile fully consumed
        // ---- stage K' (gathered) and V^T (each wave 8 rows) ----
        {
            const int kr0 = w * 8;
            for (int i = 0; i < 8; ++i) {
                const int kr = kr0 + i;
                const int grow = kt * KT + kr;
                const int i0 = p0b[grow], i1 = p1b[grow];
                const float a0 = kp[(size_t)i0 * D_ + lane];
                const float a1 = kp[(size_t)i1 * D_ + lane];
                Ks[kr][lane] = f2bf(a0);
                Ks[kr][64 + lane] = f2bf(a1);
                const float vv = vp[(size_t)grow * D_ + lane];
                Vs[lane][kr] = f2bf(vv);   // transposed store
            }
        }
        __syncthreads();

        // ---- QK^T: two 16-col subtiles, K-dim 128 = 4 MFMAs each ----
        f32x4 s0 = {}, s1 = {};
        for (int c = 0; c < 4; ++c) {
            const s16x8 kf0 = *reinterpret_cast<const s16x8*>(&Ks[fr][c * 32 + fg * 8]);
            const s16x8 kf1 = *reinterpret_cast<const s16x8*>(&Ks[16 + fr][c * 32 + fg * 8]);
            s0 = __builtin_amdgcn_mfma_f32_16x16x32_bf16(qf[c], kf0, s0, 0, 0, 0);
            s1 = __builtin_amdgcn_mfma_f32_16x16x32_bf16(qf[c], kf1, s1, 0, 0, 0);
        }

        // ---- online softmax (rows = fg*4+r; cols spread over 16 lanes) ----
        float pA[4], pB[4], alpha[4];
        for (int r = 0; r < 4; ++r) {
            const float a = s0[r] * CSCALE;
            const float bb = s1[r] * CSCALE;
            float tm = fmaxf(a, bb);
            tm = fmaxf(tm, __shfl_xor(tm, 1));
            tm = fmaxf(tm, __shfl_xor(tm, 2));
            tm = fmaxf(tm, __shfl_xor(tm, 4));
            tm = fmaxf(tm, __shfl_xor(tm, 8));
            const float mn = fmaxf(m_run[r], tm);
            alpha[r] = exp2f(m_run[r] - mn);
            m_run[r] = mn;
            const float pa = exp2f(a - mn);
            const float pb = exp2f(bb - mn);
            pA[r] = pa; pB[r] = pb;
            float rs = pa + pb;
            rs += __shfl_xor(rs, 1);
            rs += __shfl_xor(rs, 2);
            rs += __shfl_xor(rs, 4);
            rs += __shfl_xor(rs, 8);
            l_run[r] = l_run[r] * alpha[r] + rs;
        }
        for (int t2 = 0; t2 < 4; ++t2)
            for (int r = 0; r < 4; ++r)
                oacc[t2][r] *= alpha[r];

        // ---- P -> LDS (re-fragment for PV), then PV MFMAs ----
        for (int r = 0; r < 4; ++r) {
            Ps[w][fg * 4 + r][fr] = f2bf(pA[r]);
            Ps[w][fg * 4 + r][16 + fr] = f2bf(pB[r]);
        }
        const s16x8 pf = *reinterpret_cast<const s16x8*>(&Ps[w][fr][fg * 8]);
        for (int t2 = 0; t2 < 4; ++t2) {
            const s16x8 vf = *reinterpret_cast<const s16x8*>(&Vs[t2 * 16 + fr][fg * 8]);
            oacc[t2] = __builtin_amdgcn_mfma_f32_16x16x32_bf16(pf, vf, oacc[t2], 0, 0, 0);
        }
    }

    // ---- finalize: divide by l, store f32 to out[b][s][h*64+d] ----
    float inv[4];
    for (int r = 0; r < 4; ++r) inv[r] = 1.0f / l_run[r];
    const int qrow0 = qtile * QT + w * 16;
    for (int t2 = 0; t2 < 4; ++t2) {
        for (int r = 0; r < 4; ++r) {
            const int qr = qrow0 + fg * 4 + r;
            out[((size_t)b * S_ + qr) * (H_ * D_) + h * D_ + t2 * 16 + fr] = oacc[t2][r] * inv[r];
        }
    }
}

extern "C" void kernel_launch(void* const* d_in, const int* in_sizes, int n_in,
                              void* d_out, int out_size, void* d_ws, size_t ws_size,
                              hipStream_t stream) {
    (void)in_sizes; (void)n_in; (void)out_size; (void)ws_size;
    const float* q = (const float*)d_in[0];
    const float* k = (const float*)d_in[1];
    const float* v = (const float*)d_in[2];
    const float* c = (const float*)d_in[3];
    float* out = (float*)d_out;
    int* p0 = (int*)d_ws;                 // [B_, S_]
    int* p1 = p0 + B_ * S_;               // [B_, S_]
    pairs_kernel<<<dim3(8, 8), 256, 0, stream>>>(c, p0, p1);
    attn_kernel<<<dim3(16, 64), 256, 0, stream>>>(q, k, v, p0, p1, out);
}

// Round 2
// 120.804 us; speedup vs baseline: 1.4880x; 1.4880x over previous
//
#include <hip/hip_runtime.h>
#include <hip/hip_bf16.h>

#define B_ 8
#define H_ 8
#define S_ 1024
#define D_ 64
#define QT 64   // q rows per block (16 per wave)
#define KT 64   // k cols per tile

typedef float f32x4 __attribute__((ext_vector_type(4)));
typedef short s16x8 __attribute__((ext_vector_type(8)));

// (1/sqrt(2*D)) * log2(e): softmax done base-2
#define CSCALE ((float)(1.4426950408889634 / 11.313708498984761))

static __device__ __forceinline__ unsigned short f2bf(float f) {
    union { float f; unsigned u; } v; v.f = f;
    unsigned r = v.u + 0x7FFF + ((v.u >> 16) & 1);   // RNE
    return (unsigned short)(r >> 16);
}

// async global->LDS, 16B per lane; lds dest = uniform base + lane*16
static __device__ __forceinline__ void glds16(const void* g, void* l) {
    __builtin_amdgcn_global_load_lds(
        (const __attribute__((address_space(1))) unsigned int*)(uintptr_t)g,
        (__attribute__((address_space(3))) unsigned int*)(unsigned)(uintptr_t)l,
        16, 0, 0);
}

// ---------------- pairs kernel: replicate reference IoU-argmax bit-exactly ----------------
__global__ __launch_bounds__(256) void pairs_kernel(const float* __restrict__ centers,
                                                    int* __restrict__ p0,
                                                    int* __restrict__ p1) {
#pragma clang fp contract(off)
    __shared__ float x0s[S_], y0s[S_], x1s[S_], y1s[S_], areas[S_], l1s[S_];
    const int b = blockIdx.y;
    const int t = threadIdx.x;
    for (int idx = t; idx < S_; idx += 256) {
        const float4 c = *reinterpret_cast<const float4*>(centers + ((size_t)b * S_ + idx) * 4);
        const float cx = c.x, cy = c.y, hh = c.z, ww = c.w;  // order: cx, cy, h, w
        const float x0 = cx - 0.5f * ww;
        const float y0 = cy - 0.5f * hh;
        const float x1 = cx + 0.5f * ww;
        const float y1 = cy + 0.5f * hh;
        x0s[idx] = x0; y0s[idx] = y0; x1s[idx] = x1; y1s[idx] = y1;
        areas[idx] = (x1 - x0) * (y1 - y0);
        l1s[idx] = fabsf(x1 - x0) + fabsf(y1 - y0);
    }
    __syncthreads();
    const int i = blockIdx.x * 64 + (t >> 2);
    const int c4 = t & 3;
    const float x0i = x0s[i], y0i = y0s[i], x1i = x1s[i], y1i = y1s[i], ai = areas[i];
    float best = -1e38f; int arg = 0;
    const int j0 = c4 * 256;
    for (int j = j0; j < j0 + 256; ++j) {
        // NOTE: replicates reference exactly, including maximum() used for BOTH mins and maxs
        float wx = fmaxf(x1i, x1s[j]) - fmaxf(x0i, x0s[j]);
        float wy = fmaxf(y1i, y1s[j]) - fmaxf(y0i, y0s[j]);
        wx = fmaxf(wx, 0.0f);
        wy = fmaxf(wy, 0.0f);
        const float inter = wx * wy;
        const float uni = (ai + areas[j]) - inter;
        float v = inter / uni;
        if (j == i) v = v - 1.0f;   // -eye AFTER the division, as in reference
        if (v > best) { best = v; arg = j; }   // first-occurrence-of-max within chunk
    }
    // merge 4 chunks: smaller j wins ties (first-occurrence argmax)
    {
        float ob = __shfl_xor(best, 1); int oa = __shfl_xor(arg, 1);
        if (ob > best || (ob == best && oa < arg)) { best = ob; arg = oa; }
        ob = __shfl_xor(best, 2); oa = __shfl_xor(arg, 2);
        if (ob > best || (ob == best && oa < arg)) { best = ob; arg = oa; }
    }
    if (c4 == 0) {
        const int partner = arg;
        const float l1i = l1s[i], l1p = l1s[partner];
        const int keep = (l1i >= l1p) ? 1 : 0;
        p0[b * S_ + i] = keep ? i : partner;
        p1[b * S_ + i] = keep ? partner : i;
    }
}

// ---------------- prep: gathered K' -> bf16, XOR-swizzled rows ----------------
// Kg[bh][s][e'] with e' = e ^ ((s&7)<<3)  (8-element chunk swizzle within 128-elem row)
__global__ __launch_bounds__(256) void prep_k(const float* __restrict__ k,
                                              const int* __restrict__ p0,
                                              const int* __restrict__ p1,
                                              unsigned short* __restrict__ Kg) {
    const int bh = blockIdx.y;
    const int b = bh >> 3;
    const int s0 = blockIdx.x * 64;
    const int w = threadIdx.x >> 6, lane = threadIdx.x & 63;
    const float* kp = k + (size_t)bh * S_ * D_;
    const int* p0b = p0 + b * S_;
    const int* p1b = p1 + b * S_;
    for (int i = 0; i < 16; ++i) {
        const int s = s0 + w * 16 + i;
        const int i0 = p0b[s], i1 = p1b[s];
        const float a0 = kp[(size_t)i0 * D_ + lane];
        const float a1 = kp[(size_t)i1 * D_ + lane];
        const int sw = (s & 7) << 3;
        unsigned short* row = Kg + ((size_t)bh * S_ + s) * 128;
        row[lane ^ sw] = f2bf(a0);
        row[(64 + lane) ^ sw] = f2bf(a1);
    }
}

// ---------------- prep: V^T -> bf16 [bh][d][s], XOR-swizzled in 64-col tiles ----------------
__global__ __launch_bounds__(256) void prep_v(const float* __restrict__ v,
                                              unsigned short* __restrict__ Vt) {
    __shared__ float tile[64][65];
    const int bh = blockIdx.y;
    const int s0 = blockIdx.x * 64;
    const int t = threadIdx.x;
    const float* vp = v + ((size_t)bh * S_ + s0) * D_;
    const int row = t >> 2, cpart = (t & 3) * 16;
    for (int jj = 0; jj < 4; ++jj) {
        const float4 x = *reinterpret_cast<const float4*>(&vp[(size_t)row * D_ + cpart + jj * 4]);
        tile[row][cpart + jj * 4 + 0] = x.x;
        tile[row][cpart + jj * 4 + 1] = x.y;
        tile[row][cpart + jj * 4 + 2] = x.z;
        tile[row][cpart + jj * 4 + 3] = x.w;
    }
    __syncthreads();
    const int d = t >> 2;
    unsigned short* orow = Vt + ((size_t)bh * 64 + d) * S_ + s0;
    for (int cc = 0; cc < 2; ++cc) {
        const int chunk = (t & 3) * 2 + cc;       // 8-col chunk within this 64-col tile
        unsigned short h[8];
        for (int e = 0; e < 8; ++e) h[e] = f2bf(tile[chunk * 8 + e][d]);
        const int chunk2 = chunk ^ (d & 7);
        *reinterpret_cast<s16x8*>(&orow[chunk2 * 8]) = *reinterpret_cast<s16x8*>(h);
    }
}

// ---------------- fused flash attention, bf16 MFMA, global_load_lds staging ----------------
__global__ __launch_bounds__(256, 4) void attn_kernel(const float* __restrict__ q,
                                                      const unsigned short* __restrict__ Kg,
                                                      const unsigned short* __restrict__ Vt,
                                                      const int* __restrict__ p0,
                                                      const int* __restrict__ p1,
                                                      float* __restrict__ out) {
    __shared__ __align__(16) unsigned short Ks[64][128];   // 16KB, swizzled; also Q' in prologue
    __shared__ __align__(16) unsigned short Vs[64][64];    // 8KB, swizzled: [d][kk]
    __shared__ __align__(16) unsigned short Ps[4][16][72]; // per-wave P tile [q][kk], padded

    const int tid = threadIdx.x;
    const int w = tid >> 6;          // wave 0..3
    const int lane = tid & 63;
    const int qtile = blockIdx.x;    // 0..15
    const int bh = blockIdx.y;       // 0..63
    const int b = bh >> 3;
    const int h = bh & 7;

    const float* qp = q + (size_t)bh * S_ * D_;
    const unsigned short* KgB = Kg + (size_t)bh * S_ * 128;
    const unsigned short* VtB = Vt + (size_t)bh * 64 * S_;
    const int* p0b = p0 + b * S_;
    const int* p1b = p1 + b * S_;

    const int fr = lane & 15;   // fragment 16-index
    const int fg = lane >> 4;   // quadrant 0..3
    const int frs = fr & 7;     // swizzle key for LDS reads

    // ---- prologue: stage this wave's 16 Q' rows (gathered f32 -> bf16) into Ks, swizzled ----
    {
        const int r0 = w * 16;
        for (int i = 0; i < 16; ++i) {
            const int row = r0 + i;
            const int grow = qtile * QT + row;
            const int i0 = p0b[grow], i1 = p1b[grow];
            const float a0 = qp[(size_t)i0 * D_ + lane];
            const float a1 = qp[(size_t)i1 * D_ + lane];
            const int sw = (row & 7) << 3;
            Ks[row][lane ^ sw] = f2bf(a0);
            Ks[row][(64 + lane) ^ sw] = f2bf(a1);
        }
    }
    __syncthreads();
    s16x8 qf[4];
    {
        const int qrow = w * 16 + fr;
        for (int c = 0; c < 4; ++c)
            qf[c] = *reinterpret_cast<const s16x8*>(&Ks[qrow][((c * 4 + fg) ^ frs) * 8]);
    }

    f32x4 oacc[4] = {};           // O accumulator: 4 d-subtiles x 4 rows
    float m_run[4], l_run[4];
    for (int r = 0; r < 4; ++r) { m_run[r] = -1e30f; l_run[r] = 0.0f; }

    for (int kt = 0; kt < S_ / KT; ++kt) {
        __syncthreads();   // previous tile (and prologue qf reads) fully consumed
        // ---- stage K' tile (4 issues/wave) and V^T tile (2 issues/wave), async ----
        {
            const int rowK = (w * 4 + 0) * 4 + (lane >> 4);    // chunk rows: 4 rows / issue
            const size_t srcK = ((size_t)(kt * KT) + rowK) * 128 + (lane & 15) * 8;
            for (int qq = 0; qq < 4; ++qq)
                glds16(KgB + srcK + (size_t)qq * 4 * 128, &Ks[(w * 4 + qq) * 4][0]);
            const int dV = (w * 2 + 0) * 8 + (lane >> 3);      // 8 d-rows / issue
            const size_t srcV = (size_t)dV * S_ + kt * KT + (lane & 7) * 8;
            for (int qq = 0; qq < 2; ++qq)
                glds16(VtB + srcV + (size_t)qq * 8 * S_, &Vs[(w * 2 + qq) * 8][0]);
        }
        __syncthreads();

        // ---- QK^T: 4 k-col subtiles, K-dim 128 = 16 MFMAs ----
        f32x4 st[4] = {};
        for (int c = 0; c < 4; ++c) {
            for (int t2 = 0; t2 < 4; ++t2) {
                const s16x8 kf = *reinterpret_cast<const s16x8*>(
                    &Ks[t2 * 16 + fr][((c * 4 + fg) ^ frs) * 8]);
                st[t2] = __builtin_amdgcn_mfma_f32_16x16x32_bf16(qf[c], kf, st[t2], 0, 0, 0);
            }
        }

        // ---- online softmax (rows = fg*4+r; cols = t*16 + fr) ----
        float alpha[4];
        float pvv[4][4];
        for (int r = 0; r < 4; ++r) {
            const float a0 = st[0][r] * CSCALE;
            const float a1 = st[1][r] * CSCALE;
            const float a2 = st[2][r] * CSCALE;
            const float a3 = st[3][r] * CSCALE;
            float tm = fmaxf(fmaxf(a0, a1), fmaxf(a2, a3));
            tm = fmaxf(tm, __shfl_xor(tm, 1));
            tm = fmaxf(tm, __shfl_xor(tm, 2));
            tm = fmaxf(tm, __shfl_xor(tm, 4));
            tm = fmaxf(tm, __shfl_xor(tm, 8));
            const float mn = fmaxf(m_run[r], tm);
            alpha[r] = exp2f(m_run[r] - mn);
            m_run[r] = mn;
            const float e0 = exp2f(a0 - mn);
            const float e1 = exp2f(a1 - mn);
            const float e2 = exp2f(a2 - mn);
            const float e3 = exp2f(a3 - mn);
            pvv[r][0] = e0; pvv[r][1] = e1; pvv[r][2] = e2; pvv[r][3] = e3;
            float rs = (e0 + e1) + (e2 + e3);
            rs += __shfl_xor(rs, 1);
            rs += __shfl_xor(rs, 2);
            rs += __shfl_xor(rs, 4);
            rs += __shfl_xor(rs, 8);
            l_run[r] = l_run[r] * alpha[r] + rs;
        }
        for (int t2 = 0; t2 < 4; ++t2)
            for (int r = 0; r < 4; ++r)
                oacc[t2][r] *= alpha[r];

        // ---- P -> per-wave LDS (re-fragment for PV A-operand) ----
        for (int r = 0; r < 4; ++r)
            for (int t2 = 0; t2 < 4; ++t2)
                Ps[w][fg * 4 + r][t2 * 16 + fr] = f2bf(pvv[r][t2]);
        const s16x8 pf0 = *reinterpret_cast<const s16x8*>(&Ps[w][fr][fg * 8]);
        const s16x8 pf1 = *reinterpret_cast<const s16x8*>(&Ps[w][fr][32 + fg * 8]);

        // ---- PV: 4 d-subtiles x k-dim 64 = 8 MFMAs ----
        for (int t2 = 0; t2 < 4; ++t2) {
            const s16x8 vf0 = *reinterpret_cast<const s16x8*>(
                &Vs[t2 * 16 + fr][((0 * 4 + fg) ^ frs) * 8]);
            oacc[t2] = __builtin_amdgcn_mfma_f32_16x16x32_bf16(pf0, vf0, oacc[t2], 0, 0, 0);
            const s16x8 vf1 = *reinterpret_cast<const s16x8*>(
                &Vs[t2 * 16 + fr][((1 * 4 + fg) ^ frs) * 8]);
            oacc[t2] = __builtin_amdgcn_mfma_f32_16x16x32_bf16(pf1, vf1, oacc[t2], 0, 0, 0);
        }
    }

    // ---- finalize: divide by l, store f32 to out[b][s][h*64+d] ----
    float inv[4];
    for (int r = 0; r < 4; ++r) inv[r] = 1.0f / l_run[r];
    const int qrow0 = qtile * QT + w * 16;
    for (int t2 = 0; t2 < 4; ++t2) {
        for (int r = 0; r < 4; ++r) {
            const int qr = qrow0 + fg * 4 + r;
            out[((size_t)b * S_ + qr) * (H_ * D_) + h * D_ + t2 * 16 + fr] = oacc[t2][r] * inv[r];
        }
    }
}

extern "C" void kernel_launch(void* const* d_in, const int* in_sizes, int n_in,
                              void* d_out, int out_size, void* d_ws, size_t ws_size,
                              hipStream_t stream) {
    (void)in_sizes; (void)n_in; (void)out_size; (void)ws_size;
    const float* q = (const float*)d_in[0];
    const float* k = (const float*)d_in[1];
    const float* v = (const float*)d_in[2];
    const float* c = (const float*)d_in[3];
    float* out = (float*)d_out;
    int* p0 = (int*)d_ws;                                   // [B_, S_] = 32KB
    int* p1 = p0 + B_ * S_;                                 // 32KB
    unsigned short* Kg = (unsigned short*)((char*)d_ws + 65536);        // 16.8MB
    unsigned short* Vt = Kg + (size_t)B_ * H_ * S_ * 128;               // 8.4MB
    pairs_kernel<<<dim3(16, 8), 256, 0, stream>>>(c, p0, p1);
    prep_k<<<dim3(16, 64), 256, 0, stream>>>(k, p0, p1, Kg);
    prep_v<<<dim3(16, 64), 256, 0, stream>>>(v, Vt);
    attn_kernel<<<dim3(16, 64), 256, 0, stream>>>(q, Kg, Vt, p0, p1, out);
}

// Round 3
// 82.967 us; speedup vs baseline: 2.1667x; 1.4561x over previous
//
#include <hip/hip_runtime.h>
#include <hip/hip_bf16.h>

#define B_ 8
#define H_ 8
#define S_ 1024
#define D_ 64
#define QT 128  // q rows per block (32 per wave)
#define KT 64   // k cols per tile
#define NT (S_ / KT)

typedef float f32x16 __attribute__((ext_vector_type(16)));
typedef short s16x8 __attribute__((ext_vector_type(8)));
typedef unsigned int u32;

// (1/sqrt(2*D)) * log2(e): softmax done base-2; folded into Q at load time
#define CSCALE ((float)(1.4426950408889634 / 11.313708498984761))

static __device__ __forceinline__ unsigned short f2bf(float f) {
    union { float f; unsigned u; } v; v.f = f;
    unsigned r = v.u + 0x7FFF + ((v.u >> 16) & 1);   // RNE
    return (unsigned short)(r >> 16);
}

static __device__ __forceinline__ u32 cvtpk(float lo, float hi) {
    u32 r;
    asm("v_cvt_pk_bf16_f32 %0, %1, %2" : "=v"(r) : "v"(lo), "v"(hi));
    return r;
}

// async global->LDS, 16B per lane; lds dest = uniform base + lane*16
static __device__ __forceinline__ void glds16(const void* g, void* l) {
    __builtin_amdgcn_global_load_lds(
        (const __attribute__((address_space(1))) unsigned int*)(uintptr_t)g,
        (__attribute__((address_space(3))) unsigned int*)(unsigned)(uintptr_t)l,
        16, 0, 0);
}

// ---------------- pairs kernel: replicate reference IoU-argmax bit-exactly ----------------
__global__ __launch_bounds__(256) void pairs_kernel(const float* __restrict__ centers,
                                                    int* __restrict__ p0,
                                                    int* __restrict__ p1) {
#pragma clang fp contract(off)
    __shared__ float x0s[S_], y0s[S_], x1s[S_], y1s[S_], areas[S_], l1s[S_];
    const int b = blockIdx.y;
    const int t = threadIdx.x;
    for (int idx = t; idx < S_; idx += 256) {
        const float4 c = *reinterpret_cast<const float4*>(centers + ((size_t)b * S_ + idx) * 4);
        const float cx = c.x, cy = c.y, hh = c.z, ww = c.w;  // order: cx, cy, h, w
        const float x0 = cx - 0.5f * ww;
        const float y0 = cy - 0.5f * hh;
        const float x1 = cx + 0.5f * ww;
        const float y1 = cy + 0.5f * hh;
        x0s[idx] = x0; y0s[idx] = y0; x1s[idx] = x1; y1s[idx] = y1;
        areas[idx] = (x1 - x0) * (y1 - y0);
        l1s[idx] = fabsf(x1 - x0) + fabsf(y1 - y0);
    }
    __syncthreads();
    const int i = blockIdx.x * 32 + (t >> 3);
    const int c8 = t & 7;
    const float x0i = x0s[i], y0i = y0s[i], x1i = x1s[i], y1i = y1s[i], ai = areas[i];
    float best = -1e38f; int arg = 0;
    const int j0 = c8 * 128;
    for (int j = j0; j < j0 + 128; ++j) {
        // NOTE: replicates reference exactly, including maximum() used for BOTH mins and maxs
        float wx = fmaxf(x1i, x1s[j]) - fmaxf(x0i, x0s[j]);
        float wy = fmaxf(y1i, y1s[j]) - fmaxf(y0i, y0s[j]);
        wx = fmaxf(wx, 0.0f);
        wy = fmaxf(wy, 0.0f);
        const float inter = wx * wy;
        const float uni = (ai + areas[j]) - inter;
        float v = inter / uni;
        if (j == i) v = v - 1.0f;   // -eye AFTER the division, as in reference
        if (v > best) { best = v; arg = j; }   // first-occurrence-of-max within chunk
    }
    // merge 8 chunks: smaller j wins ties (first-occurrence argmax)
    #pragma unroll
    for (int m = 1; m <= 4; m <<= 1) {
        const float ob = __shfl_xor(best, m);
        const int oa = __shfl_xor(arg, m);
        if (ob > best || (ob == best && oa < arg)) { best = ob; arg = oa; }
    }
    if (c8 == 0) {
        const int partner = arg;
        const float l1i = l1s[i], l1p = l1s[partner];
        const int keep = (l1i >= l1p) ? 1 : 0;
        p0[b * S_ + i] = keep ? i : partner;
        p1[b * S_ + i] = keep ? partner : i;
    }
}

// ---------------- prep (fused): gathered K' bf16 (swizzled) + V^T bf16 (swizzled) ----------------
// Kg[bh][s][e ^ ((s&7)<<3)], Vt[bh][d][ (chunk ^ (d&7))*8 + e ] per 64-col tile
__global__ __launch_bounds__(256) void prep_kv(const float* __restrict__ k,
                                               const float* __restrict__ v,
                                               const int* __restrict__ p0,
                                               const int* __restrict__ p1,
                                               unsigned short* __restrict__ Kg,
                                               unsigned short* __restrict__ Vt) {
    __shared__ float tile[64][65];
    const int bh = blockIdx.y;
    const int b = bh >> 3;
    const int s0 = blockIdx.x * 64;
    const int t = threadIdx.x;
    const int w = t >> 6, lane = t & 63;
    // --- K gather part ---
    {
        const float* kp = k + (size_t)bh * S_ * D_;
        const int* p0b = p0 + b * S_;
        const int* p1b = p1 + b * S_;
        for (int i = 0; i < 16; ++i) {
            const int s = s0 + w * 16 + i;
            const int i0 = p0b[s], i1 = p1b[s];
            const float a0 = kp[(size_t)i0 * D_ + lane];
            const float a1 = kp[(size_t)i1 * D_ + lane];
            const int sw = (s & 7) << 3;
            unsigned short* row = Kg + ((size_t)bh * S_ + s) * 128;
            row[lane ^ sw] = f2bf(a0);
            row[(64 + lane) ^ sw] = f2bf(a1);
        }
    }
    // --- V transpose part ---
    {
        const float* vp = v + ((size_t)bh * S_ + s0) * D_;
        const int row = t >> 2, cpart = (t & 3) * 16;
        for (int jj = 0; jj < 4; ++jj) {
            const float4 x = *reinterpret_cast<const float4*>(&vp[(size_t)row * D_ + cpart + jj * 4]);
            tile[row][cpart + jj * 4 + 0] = x.x;
            tile[row][cpart + jj * 4 + 1] = x.y;
            tile[row][cpart + jj * 4 + 2] = x.z;
            tile[row][cpart + jj * 4 + 3] = x.w;
        }
        __syncthreads();
        const int d = t >> 2;
        unsigned short* orow = Vt + ((size_t)bh * 64 + d) * S_ + s0;
        for (int cc = 0; cc < 2; ++cc) {
            const int chunk = (t & 3) * 2 + cc;       // 8-col chunk within this 64-col tile
            unsigned short hh[8];
            for (int e = 0; e < 8; ++e) hh[e] = f2bf(tile[chunk * 8 + e][d]);
            const int chunk2 = chunk ^ (d & 7);
            *reinterpret_cast<s16x8*>(&orow[chunk2 * 8]) = *reinterpret_cast<s16x8*>(hh);
        }
    }
}

// ---------------- fused flash attention: swapped QK^T (32x32 MFMA), in-reg softmax/P ----------------
__global__ __launch_bounds__(256, 2) void attn_kernel(const float* __restrict__ q,
                                                      const unsigned short* __restrict__ Kg,
                                                      const unsigned short* __restrict__ Vt,
                                                      const int* __restrict__ p0,
                                                      const int* __restrict__ p1,
                                                      float* __restrict__ out) {
    __shared__ __align__(16) unsigned short Ks[2][KT][128];  // 32KB dbuf, pre-swizzled
    __shared__ __align__(16) unsigned short Vs[2][D_][KT];   // 16KB dbuf, pre-swizzled [d][kk]

    const int tid = threadIdx.x;
    const int w = tid >> 6;          // wave 0..3
    const int lane = tid & 63;
    const int qc = lane & 31;        // q-row within wave tile / kcol within K-tile
    const int hi = lane >> 5;
    const int qtile = blockIdx.x;    // 0..7
    const int bh = blockIdx.y;       // 0..63
    const int b = bh >> 3;
    const int h = bh & 7;

    const float* qp = q + (size_t)bh * S_ * D_;
    const unsigned short* KgB = Kg + (size_t)bh * S_ * 128;
    const unsigned short* VtB = Vt + (size_t)bh * D_ * S_;

    // ---- stage tile 0 into buf 0 (async) ----
    {
        const int rK = lane >> 4;
        const size_t cK = (size_t)(lane & 15) * 8;
        #pragma unroll
        for (int qq = 0; qq < 4; ++qq)
            glds16(KgB + ((size_t)((w * 4 + qq) * 4 + rK)) * 128 + cK, &Ks[0][(w * 4 + qq) * 4][0]);
        const int rV = lane >> 3;
        const size_t cV = (size_t)(lane & 7) * 8;
        #pragma unroll
        for (int qq = 0; qq < 2; ++qq)
            glds16(VtB + ((size_t)((w * 2 + qq) * 8 + rV)) * S_ + cV, &Vs[0][(w * 2 + qq) * 8][0]);
    }

    // ---- gather this lane's Q' row slices into B-fragments (pre-scaled by CSCALE) ----
    s16x8 qf[8];
    {
        const int qr = qtile * QT + w * 32 + qc;
        const int i0 = p0[b * S_ + qr], i1 = p1[b * S_ + qr];
        #pragma unroll
        for (int p = 0; p < 8; ++p) {
            const int k0 = 16 * p + 8 * hi;
            const float* src = (p < 4) ? (qp + (size_t)i0 * D_ + k0)
                                       : (qp + (size_t)i1 * D_ + (k0 - 64));
            const float4 f0 = *reinterpret_cast<const float4*>(src);
            const float4 f1 = *reinterpret_cast<const float4*>(src + 4);
            union { u32 u[4]; s16x8 v; } pk;
            pk.u[0] = cvtpk(f0.x * CSCALE, f0.y * CSCALE);
            pk.u[1] = cvtpk(f0.z * CSCALE, f0.w * CSCALE);
            pk.u[2] = cvtpk(f1.x * CSCALE, f1.y * CSCALE);
            pk.u[3] = cvtpk(f1.z * CSCALE, f1.w * CSCALE);
            qf[p] = pk.v;
        }
    }
    __syncthreads();

    f32x16 oacc0 = {}, oacc1 = {};   // O^T accumulators: d-tiles 0/1 x qrow=qc
    float m_run = -1e30f, l_run = 0.0f;
    const int swz = qc & 7;

    for (int kt = 0; kt < NT; ++kt) {
        const int bf = kt & 1;
        // ---- stage next tile into other buffer (async, overlaps compute) ----
        if (kt + 1 < NT) {
            const int rK = lane >> 4;
            const size_t cK = (size_t)(lane & 15) * 8;
            const size_t kbase = (size_t)((kt + 1) * KT) * 128;
            #pragma unroll
            for (int qq = 0; qq < 4; ++qq)
                glds16(KgB + kbase + ((size_t)((w * 4 + qq) * 4 + rK)) * 128 + cK,
                       &Ks[bf ^ 1][(w * 4 + qq) * 4][0]);
            const int rV = lane >> 3;
            const size_t cV = (size_t)((kt + 1) * KT) + (size_t)(lane & 7) * 8;
            #pragma unroll
            for (int qq = 0; qq < 2; ++qq)
                glds16(VtB + ((size_t)((w * 2 + qq) * 8 + rV)) * S_ + cV,
                       &Vs[bf ^ 1][(w * 2 + qq) * 8][0]);
        }

        // ---- swapped QK^T: D[kcol][qrow], two 32-kcol tiles, kdim 128 = 16 MFMAs ----
        f32x16 st0 = {}, st1 = {};
        #pragma unroll
        for (int p = 0; p < 8; ++p) {
            const int ch = (2 * p + hi) ^ swz;
            const s16x8 kf0 = *reinterpret_cast<const s16x8*>(&Ks[bf][qc][ch * 8]);
            st0 = __builtin_amdgcn_mfma_f32_32x32x16_bf16(kf0, qf[p], st0, 0, 0, 0);
            const s16x8 kf1 = *reinterpret_cast<const s16x8*>(&Ks[bf][32 + qc][ch * 8]);
            st1 = __builtin_amdgcn_mfma_f32_32x32x16_bf16(kf1, qf[p], st1, 0, 0, 0);
        }

        // ---- online softmax: all 64 kcols of qrow qc live in this lane pair (hi 0/1) ----
        float t16[16];
        #pragma unroll
        for (int i = 0; i < 16; ++i) t16[i] = fmaxf(st0[i], st1[i]);
        #pragma unroll
        for (int i = 0; i < 8; ++i) t16[i] = fmaxf(t16[i], t16[i + 8]);
        #pragma unroll
        for (int i = 0; i < 4; ++i) t16[i] = fmaxf(t16[i], t16[i + 4]);
        float mx = fmaxf(fmaxf(t16[0], t16[1]), fmaxf(t16[2], t16[3]));
        mx = fmaxf(mx, __shfl_xor(mx, 32));
        const float mn = fmaxf(m_run, mx);
        const float alpha = exp2f(m_run - mn);
        m_run = mn;
        #pragma unroll
        for (int i = 0; i < 16; ++i) {
            st0[i] = exp2f(st0[i] - mn);
            st1[i] = exp2f(st1[i] - mn);
        }
        float a16[16];
        #pragma unroll
        for (int i = 0; i < 16; ++i) a16[i] = st0[i] + st1[i];
        #pragma unroll
        for (int i = 0; i < 8; ++i) a16[i] += a16[i + 8];
        #pragma unroll
        for (int i = 0; i < 4; ++i) a16[i] += a16[i + 4];
        float ps = (a16[0] + a16[1]) + (a16[2] + a16[3]);
        ps += __shfl_xor(ps, 32);
        l_run = l_run * alpha + ps;
        oacc0 *= alpha;
        oacc1 *= alpha;

        // ---- pack P to bf16 pairs (in-register) ----
        u32 U0[8], U1[8];
        #pragma unroll
        for (int i = 0; i < 8; ++i) {
            U0[i] = cvtpk(st0[2 * i], st0[2 * i + 1]);
            U1[i] = cvtpk(st1[2 * i], st1[2 * i + 1]);
        }

        // ---- PV: O^T += V^T . P^T ; B-frag built by cross-half exchange ----
        #pragma unroll
        for (int s = 0; s < 4; ++s) {
            const u32* Ut = (s < 2) ? U0 : U1;
            const int a = 4 * (s & 1);
            const u32 sendA = hi ? Ut[a] : Ut[a + 2];
            const u32 recvA = __shfl_xor(sendA, 32);
            const u32 w0 = hi ? recvA : Ut[a];
            const u32 w2 = hi ? Ut[a + 2] : recvA;
            const u32 sendB = hi ? Ut[a + 1] : Ut[a + 3];
            const u32 recvB = __shfl_xor(sendB, 32);
            const u32 w1 = hi ? recvB : Ut[a + 1];
            const u32 w3 = hi ? Ut[a + 3] : recvB;
            union { u32 u[4]; s16x8 v; } pf;
            pf.u[0] = w0; pf.u[1] = w1; pf.u[2] = w2; pf.u[3] = w3;
            const int ch = (2 * s + hi) ^ swz;
            const s16x8 vf0 = *reinterpret_cast<const s16x8*>(&Vs[bf][qc][ch * 8]);
            oacc0 = __builtin_amdgcn_mfma_f32_32x32x16_bf16(vf0, pf.v, oacc0, 0, 0, 0);
            const s16x8 vf1 = *reinterpret_cast<const s16x8*>(&Vs[bf][32 + qc][ch * 8]);
            oacc1 = __builtin_amdgcn_mfma_f32_32x32x16_bf16(vf1, pf.v, oacc1, 0, 0, 0);
        }
        __syncthreads();   // drains staged loads; all waves done reading buf
    }

    // ---- epilogue: O^T[d][qrow=qc] -> out[b][qr][h*64+d], divide by l ----
    const float invl = 1.0f / l_run;
    const int qrg = qtile * QT + w * 32 + qc;
    float* orow = out + ((size_t)b * S_ + qrg) * (H_ * D_) + h * D_;
    #pragma unroll
    for (int rq = 0; rq < 4; ++rq) {
        const float4 v0 = { oacc0[4 * rq] * invl, oacc0[4 * rq + 1] * invl,
                            oacc0[4 * rq + 2] * invl, oacc0[4 * rq + 3] * invl };
        *reinterpret_cast<float4*>(orow + 8 * rq + 4 * hi) = v0;
        const float4 v1 = { oacc1[4 * rq] * invl, oacc1[4 * rq + 1] * invl,
                            oacc1[4 * rq + 2] * invl, oacc1[4 * rq + 3] * invl };
        *reinterpret_cast<float4*>(orow + 32 + 8 * rq + 4 * hi) = v1;
    }
}

extern "C" void kernel_launch(void* const* d_in, const int* in_sizes, int n_in,
                              void* d_out, int out_size, void* d_ws, size_t ws_size,
                              hipStream_t stream) {
    (void)in_sizes; (void)n_in; (void)out_size; (void)ws_size;
    const float* q = (const float*)d_in[0];
    const float* k = (const float*)d_in[1];
    const float* v = (const float*)d_in[2];
    const float* c = (const float*)d_in[3];
    float* out = (float*)d_out;
    int* p0 = (int*)d_ws;                                   // [B_, S_] = 32KB
    int* p1 = p0 + B_ * S_;                                 // 32KB
    unsigned short* Kg = (unsigned short*)((char*)d_ws + 65536);        // 16.8MB
    unsigned short* Vt = Kg + (size_t)B_ * H_ * S_ * 128;               // 8.4MB
    pairs_kernel<<<dim3(32, 8), 256, 0, stream>>>(c, p0, p1);
    prep_kv<<<dim3(16, 64), 256, 0, stream>>>(k, v, p0, p1, Kg, Vt);
    attn_kernel<<<dim3(8, 64), 256, 0, stream>>>(q, Kg, Vt, p0, p1, out);
}

// Round 4
// 81.659 us; speedup vs baseline: 2.2013x; 1.0160x over previous
//
#include <hip/hip_runtime.h>
#include <hip/hip_bf16.h>

#define B_ 8
#define H_ 8
#define S_ 1024
#define D_ 64
#define QT 128  // q rows per block (32 per wave)
#define KT 64   // k cols per tile
#define NT (S_ / KT)

typedef float f32x16 __attribute__((ext_vector_type(16)));
typedef short s16x8 __attribute__((ext_vector_type(8)));
typedef unsigned int u32;

// (1/sqrt(2*D)) * log2(e): softmax done base-2; folded into Q at load time
#define CSCALE ((float)(1.4426950408889634 / 11.313708498984761))

static __device__ __forceinline__ unsigned short f2bf(float f) {
    union { float f; unsigned u; } v; v.f = f;
    unsigned r = v.u + 0x7FFF + ((v.u >> 16) & 1);   // RNE
    return (unsigned short)(r >> 16);
}

static __device__ __forceinline__ u32 cvtpk(float lo, float hi) {
    u32 r;
    asm("v_cvt_pk_bf16_f32 %0, %1, %2" : "=v"(r) : "v"(lo), "v"(hi));
    return r;
}

// async global->LDS, 16B per lane; lds dest = uniform base + lane*16
static __device__ __forceinline__ void glds16(const void* g, void* l) {
    __builtin_amdgcn_global_load_lds(
        (const __attribute__((address_space(1))) unsigned int*)(uintptr_t)g,
        (__attribute__((address_space(3))) unsigned int*)(unsigned)(uintptr_t)l,
        16, 0, 0);
}

// ---------------- pairs kernel: replicate reference IoU-argmax bit-exactly ----------------
__global__ __launch_bounds__(256) void pairs_kernel(const float* __restrict__ centers,
                                                    int* __restrict__ p0,
                                                    int* __restrict__ p1) {
#pragma clang fp contract(off)
    __shared__ float x0s[S_], y0s[S_], x1s[S_], y1s[S_], areas[S_], l1s[S_];
    const int b = blockIdx.y;
    const int t = threadIdx.x;
    for (int idx = t; idx < S_; idx += 256) {
        const float4 c = *reinterpret_cast<const float4*>(centers + ((size_t)b * S_ + idx) * 4);
        const float cx = c.x, cy = c.y, hh = c.z, ww = c.w;  // order: cx, cy, h, w
        const float x0 = cx - 0.5f * ww;
        const float y0 = cy - 0.5f * hh;
        const float x1 = cx + 0.5f * ww;
        const float y1 = cy + 0.5f * hh;
        x0s[idx] = x0; y0s[idx] = y0; x1s[idx] = x1; y1s[idx] = y1;
        areas[idx] = (x1 - x0) * (y1 - y0);
        l1s[idx] = fabsf(x1 - x0) + fabsf(y1 - y0);
    }
    __syncthreads();
    const int i = blockIdx.x * 32 + (t >> 3);
    const int c8 = t & 7;
    const float x0i = x0s[i], y0i = y0s[i], x1i = x1s[i], y1i = y1s[i], ai = areas[i];
    float best = -1e38f; int arg = 0;
    const int j0 = c8 * 128;
    for (int j = j0; j < j0 + 128; ++j) {
        // NOTE: replicates reference exactly, including maximum() used for BOTH mins and maxs
        float wx = fmaxf(x1i, x1s[j]) - fmaxf(x0i, x0s[j]);
        float wy = fmaxf(y1i, y1s[j]) - fmaxf(y0i, y0s[j]);
        wx = fmaxf(wx, 0.0f);
        wy = fmaxf(wy, 0.0f);
        const float inter = wx * wy;
        const float uni = (ai + areas[j]) - inter;
        float v = inter / uni;
        if (j == i) v = v - 1.0f;   // -eye AFTER the division, as in reference
        if (v > best) { best = v; arg = j; }   // first-occurrence-of-max within chunk
    }
    // merge 8 chunks: smaller j wins ties (first-occurrence argmax)
    #pragma unroll
    for (int m = 1; m <= 4; m <<= 1) {
        const float ob = __shfl_xor(best, m);
        const int oa = __shfl_xor(arg, m);
        if (ob > best || (ob == best && oa < arg)) { best = ob; arg = oa; }
    }
    if (c8 == 0) {
        const int partner = arg;
        const float l1i = l1s[i], l1p = l1s[partner];
        const int keep = (l1i >= l1p) ? 1 : 0;
        p0[b * S_ + i] = keep ? i : partner;
        p1[b * S_ + i] = keep ? partner : i;
    }
}

// ---------------- prep (fused): gathered K' bf16 (swizzled) + V^T bf16 (swizzled) ----------------
// Kg[bh][s][e ^ ((s&7)<<3)], Vt[bh][d][ (chunk ^ (d&7))*8 + e ] per 64-col tile
__global__ __launch_bounds__(256) void prep_kv(const float* __restrict__ k,
                                               const float* __restrict__ v,
                                               const int* __restrict__ p0,
                                               const int* __restrict__ p1,
                                               unsigned short* __restrict__ Kg,
                                               unsigned short* __restrict__ Vt) {
    __shared__ float tile[64][65];
    const int gid = blockIdx.x;                 // XCD-swizzled 1D grid: 1024 blocks
    const int stile = (gid >> 3) & 15;
    const int bh = ((gid >> 7) << 3) | (gid & 7);
    const int b = bh >> 3;
    const int s0 = stile * 64;
    const int t = threadIdx.x;
    // --- K gather part: one 16B store per lane per row-group ---
    {
        const float* kp = k + (size_t)bh * S_ * D_;
        const int* p0b = p0 + b * S_;
        const int* p1b = p1 + b * S_;
        const int chunk = t & 15;               // 16 chunks of 8 elems in the 128-wide row
        const int rsub = t >> 4;                // 16 rows per pass
        for (int it = 0; it < 4; ++it) {
            const int s = s0 + it * 16 + rsub;
            const int i0 = p0b[s], i1 = p1b[s];
            const float* src = (chunk < 8) ? (kp + (size_t)i0 * D_ + chunk * 8)
                                           : (kp + (size_t)i1 * D_ + (chunk - 8) * 8);
            const float4 f0 = *reinterpret_cast<const float4*>(src);
            const float4 f1 = *reinterpret_cast<const float4*>(src + 4);
            union { u32 u[4]; s16x8 v; } pk;
            pk.u[0] = cvtpk(f0.x, f0.y);
            pk.u[1] = cvtpk(f0.z, f0.w);
            pk.u[2] = cvtpk(f1.x, f1.y);
            pk.u[3] = cvtpk(f1.z, f1.w);
            unsigned short* row = Kg + ((size_t)bh * S_ + s) * 128;
            *reinterpret_cast<s16x8*>(row + (size_t)(chunk ^ (s & 7)) * 8) = pk.v;
        }
    }
    // --- V transpose part ---
    {
        const float* vp = v + ((size_t)bh * S_ + s0) * D_;
        const int row = t >> 2, cpart = (t & 3) * 16;
        for (int jj = 0; jj < 4; ++jj) {
            const float4 x = *reinterpret_cast<const float4*>(&vp[(size_t)row * D_ + cpart + jj * 4]);
            tile[row][cpart + jj * 4 + 0] = x.x;
            tile[row][cpart + jj * 4 + 1] = x.y;
            tile[row][cpart + jj * 4 + 2] = x.z;
            tile[row][cpart + jj * 4 + 3] = x.w;
        }
        __syncthreads();
        const int d = t >> 2;
        unsigned short* orow = Vt + ((size_t)bh * 64 + d) * S_ + s0;
        for (int cc = 0; cc < 2; ++cc) {
            const int chunk = (t & 3) * 2 + cc;       // 8-col chunk within this 64-col tile
            unsigned short hh[8];
            for (int e = 0; e < 8; ++e) hh[e] = f2bf(tile[chunk * 8 + e][d]);
            const int chunk2 = chunk ^ (d & 7);
            *reinterpret_cast<s16x8*>(&orow[chunk2 * 8]) = *reinterpret_cast<s16x8*>(hh);
        }
    }
}

// ---------------- fused flash attention: swapped QK^T (32x32 MFMA), in-reg softmax/P ----------------
// Triple-buffered LDS + counted vmcnt + raw barriers (T3/T4), setprio (T5), defer-max (T13)
__global__ __launch_bounds__(256, 2) void attn_kernel(const float* __restrict__ q,
                                                      const unsigned short* __restrict__ Kg,
                                                      const unsigned short* __restrict__ Vt,
                                                      const int* __restrict__ p0,
                                                      const int* __restrict__ p1,
                                                      float* __restrict__ out) {
    __shared__ __align__(16) unsigned short Ks[3][KT][128];  // 48KB, pre-swizzled
    __shared__ __align__(16) unsigned short Vs[3][D_][KT];   // 24KB, pre-swizzled [d][kk]

    const int tid = threadIdx.x;
    const int w = tid >> 6;          // wave 0..3
    const int lane = tid & 63;
    const int qc = lane & 31;        // q-row within wave tile / kcol within K-tile
    const int hi = lane >> 5;
    const int gid = blockIdx.x;      // XCD-swizzled 1D grid: 512 blocks
    const int qtile = (gid >> 3) & 7;
    const int bh = ((gid >> 6) << 3) | (gid & 7);
    const int b = bh >> 3;
    const int h = bh & 7;

    const float* qp = q + (size_t)bh * S_ * D_;
    const unsigned short* KgB = Kg + (size_t)bh * S_ * 128;
    const unsigned short* VtB = Vt + (size_t)bh * D_ * S_;

    // ---- gather this lane's Q' row slices into B-fragments (pre-scaled by CSCALE) ----
    // done FIRST so the cvtpk drain doesn't flush the staged tiles
    s16x8 qf[8];
    {
        const int qr = qtile * QT + w * 32 + qc;
        const int i0 = p0[b * S_ + qr], i1 = p1[b * S_ + qr];
        #pragma unroll
        for (int p = 0; p < 8; ++p) {
            const int k0 = 16 * p + 8 * hi;
            const float* src = (p < 4) ? (qp + (size_t)i0 * D_ + k0)
                                       : (qp + (size_t)i1 * D_ + (k0 - 64));
            const float4 f0 = *reinterpret_cast<const float4*>(src);
            const float4 f1 = *reinterpret_cast<const float4*>(src + 4);
            union { u32 u[4]; s16x8 v; } pk;
            pk.u[0] = cvtpk(f0.x * CSCALE, f0.y * CSCALE);
            pk.u[1] = cvtpk(f0.z * CSCALE, f0.w * CSCALE);
            pk.u[2] = cvtpk(f1.x * CSCALE, f1.y * CSCALE);
            pk.u[3] = cvtpk(f1.z * CSCALE, f1.w * CSCALE);
            qf[p] = pk.v;
        }
    }

    // ---- staging helper: 6 x glds16 per wave per tile ----
    const int rK = lane >> 4;
    const size_t cK = (size_t)(lane & 15) * 8;
    const int rV = lane >> 3;
    const size_t cV8 = (size_t)(lane & 7) * 8;
    auto STAGE = [&](int kt, int bf) {
        const size_t kbase = (size_t)(kt * KT) * 128;
        #pragma unroll
        for (int qq = 0; qq < 4; ++qq)
            glds16(KgB + kbase + ((size_t)((w * 4 + qq) * 4 + rK)) * 128 + cK,
                   &Ks[bf][(w * 4 + qq) * 4][0]);
        #pragma unroll
        for (int qq = 0; qq < 2; ++qq)
            glds16(VtB + ((size_t)((w * 2 + qq) * 8 + rV)) * S_ + (size_t)(kt * KT) + cV8,
                   &Vs[bf][(w * 2 + qq) * 8][0]);
    };
    STAGE(0, 0);
    STAGE(1, 1);

    f32x16 oacc0 = {}, oacc1 = {};   // O^T accumulators: d-tiles 0/1 x qrow=qc
    float m_run = -1e30f, l_run = 0.0f;
    const int swz = qc & 7;
    int cur = 0, nxt2 = 2;

    for (int kt = 0; kt < NT; ++kt) {
        // counted wait: outstanding = tiles kt,kt+1 (12 loads) -> vmcnt(6) leaves kt+1 in flight
        if (kt + 1 < NT) asm volatile("s_waitcnt vmcnt(6)" ::: "memory");
        else             asm volatile("s_waitcnt vmcnt(0)" ::: "memory");
        __builtin_amdgcn_s_barrier();   // all waves' tile-kt landed; all done reading buf[nxt2]
        if (kt + 2 < NT) STAGE(kt + 2, nxt2);

        const unsigned short(*KsC)[128] = Ks[cur];
        const unsigned short(*VsC)[KT] = Vs[cur];

        // ---- swapped QK^T: D[kcol][qrow], two 32-kcol tiles, kdim 128 = 16 MFMAs ----
        f32x16 st0 = {}, st1 = {};
        __builtin_amdgcn_s_setprio(1);
        #pragma unroll
        for (int p = 0; p < 8; ++p) {
            const int ch = (2 * p + hi) ^ swz;
            const s16x8 kf0 = *reinterpret_cast<const s16x8*>(&KsC[qc][ch * 8]);
            st0 = __builtin_amdgcn_mfma_f32_32x32x16_bf16(kf0, qf[p], st0, 0, 0, 0);
            const s16x8 kf1 = *reinterpret_cast<const s16x8*>(&KsC[32 + qc][ch * 8]);
            st1 = __builtin_amdgcn_mfma_f32_32x32x16_bf16(kf1, qf[p], st1, 0, 0, 0);
        }
        __builtin_amdgcn_s_setprio(0);

        // ---- online softmax: all 64 kcols of qrow qc live in this lane pair (hi 0/1) ----
        float t16[16];
        #pragma unroll
        for (int i = 0; i < 16; ++i) t16[i] = fmaxf(st0[i], st1[i]);
        #pragma unroll
        for (int i = 0; i < 8; ++i) t16[i] = fmaxf(t16[i], t16[i + 8]);
        #pragma unroll
        for (int i = 0; i < 4; ++i) t16[i] = fmaxf(t16[i], t16[i + 4]);
        float mx = fmaxf(fmaxf(t16[0], t16[1]), fmaxf(t16[2], t16[3]));
        mx = fmaxf(mx, __shfl_xor(mx, 32));
        // defer-max (T13): skip rescale while max growth <= 8 (values bounded by 2^8)
        if (!__all(mx <= m_run + 8.0f)) {
            const float mn = fmaxf(m_run, mx);
            const float alpha = exp2f(m_run - mn);
            m_run = mn;
            l_run *= alpha;
            oacc0 *= alpha;
            oacc1 *= alpha;
        }
        #pragma unroll
        for (int i = 0; i < 16; ++i) {
            st0[i] = exp2f(st0[i] - m_run);
            st1[i] = exp2f(st1[i] - m_run);
        }
        float a16[16];
        #pragma unroll
        for (int i = 0; i < 16; ++i) a16[i] = st0[i] + st1[i];
        #pragma unroll
        for (int i = 0; i < 8; ++i) a16[i] += a16[i + 8];
        #pragma unroll
        for (int i = 0; i < 4; ++i) a16[i] += a16[i + 4];
        float ps = (a16[0] + a16[1]) + (a16[2] + a16[3]);
        ps += __shfl_xor(ps, 32);
        l_run += ps;

        // ---- pack P to bf16 pairs (in-register) ----
        u32 U0[8], U1[8];
        #pragma unroll
        for (int i = 0; i < 8; ++i) {
            U0[i] = cvtpk(st0[2 * i], st0[2 * i + 1]);
            U1[i] = cvtpk(st1[2 * i], st1[2 * i + 1]);
        }

        // ---- PV: O^T += V^T . P^T ; B-frag built by cross-half exchange ----
        #pragma unroll
        for (int s = 0; s < 4; ++s) {
            const u32* Ut = (s < 2) ? U0 : U1;
            const int a = 4 * (s & 1);
            const u32 sendA = hi ? Ut[a] : Ut[a + 2];
            const u32 recvA = __shfl_xor(sendA, 32);
            const u32 w0 = hi ? recvA : Ut[a];
            const u32 w2 = hi ? Ut[a + 2] : recvA;
            const u32 sendB = hi ? Ut[a + 1] : Ut[a + 3];
            const u32 recvB = __shfl_xor(sendB, 32);
            const u32 w1 = hi ? recvB : Ut[a + 1];
            const u32 w3 = hi ? Ut[a + 3] : recvB;
            union { u32 u[4]; s16x8 v; } pf;
            pf.u[0] = w0; pf.u[1] = w1; pf.u[2] = w2; pf.u[3] = w3;
            const int ch = (2 * s + hi) ^ swz;
            __builtin_amdgcn_s_setprio(1);
            const s16x8 vf0 = *reinterpret_cast<const s16x8*>(&VsC[qc][ch * 8]);
            oacc0 = __builtin_amdgcn_mfma_f32_32x32x16_bf16(vf0, pf.v, oacc0, 0, 0, 0);
            const s16x8 vf1 = *reinterpret_cast<const s16x8*>(&VsC[32 + qc][ch * 8]);
            oacc1 = __builtin_amdgcn_mfma_f32_32x32x16_bf16(vf1, pf.v, oacc1, 0, 0, 0);
            __builtin_amdgcn_s_setprio(0);
        }
        cur = (cur + 1 == 3) ? 0 : cur + 1;
        nxt2 = (nxt2 + 1 == 3) ? 0 : nxt2 + 1;
    }

    // ---- epilogue: O^T[d][qrow=qc] -> out[b][qr][h*64+d], divide by l ----
    const float invl = 1.0f / l_run;
    const int qrg = qtile * QT + w * 32 + qc;
    float* orow = out + ((size_t)b * S_ + qrg) * (H_ * D_) + h * D_;
    #pragma unroll
    for (int rq = 0; rq < 4; ++rq) {
        const float4 v0 = { oacc0[4 * rq] * invl, oacc0[4 * rq + 1] * invl,
                            oacc0[4 * rq + 2] * invl, oacc0[4 * rq + 3] * invl };
        *reinterpret_cast<float4*>(orow + 8 * rq + 4 * hi) = v0;
        const float4 v1 = { oacc1[4 * rq] * invl, oacc1[4 * rq + 1] * invl,
                            oacc1[4 * rq + 2] * invl, oacc1[4 * rq + 3] * invl };
        *reinterpret_cast<float4*>(orow + 32 + 8 * rq + 4 * hi) = v1;
    }
}

extern "C" void kernel_launch(void* const* d_in, const int* in_sizes, int n_in,
                              void* d_out, int out_size, void* d_ws, size_t ws_size,
                              hipStream_t stream) {
    (void)in_sizes; (void)n_in; (void)out_size; (void)ws_size;
    const float* q = (const float*)d_in[0];
    const float* k = (const float*)d_in[1];
    const float* v = (const float*)d_in[2];
    const float* c = (const float*)d_in[3];
    float* out = (float*)d_out;
    int* p0 = (int*)d_ws;                                   // [B_, S_] = 32KB
    int* p1 = p0 + B_ * S_;                                 // 32KB
    unsigned short* Kg = (unsigned short*)((char*)d_ws + 65536);        // 16.8MB
    unsigned short* Vt = Kg + (size_t)B_ * H_ * S_ * 128;               // 8.4MB
    pairs_kernel<<<dim3(32, 8), 256, 0, stream>>>(c, p0, p1);
    prep_kv<<<dim3(1024), 256, 0, stream>>>(k, v, p0, p1, Kg, Vt);
    attn_kernel<<<dim3(512), 256, 0, stream>>>(q, Kg, Vt, p0, p1, out);
}